// Round 15
// baseline (151.849 us; speedup 1.0000x reference)
//
#include <hip/hip_runtime.h>
#include <math.h>

typedef float vf2 __attribute__((ext_vector_type(2)));

// ---------------- packed dual-fp32 helpers (VOP3P) ----------------
__device__ __forceinline__ vf2 pk_fma(vf2 a, vf2 b, vf2 c) {
    vf2 d;
    asm("v_pk_fma_f32 %0, %1, %2, %3" : "=v"(d) : "v"(a), "v"(b), "v"(c));
    return d;
}
__device__ __forceinline__ vf2 pk_mul(vf2 a, vf2 b) {
    vf2 d;
    asm("v_pk_mul_f32 %0, %1, %2" : "=v"(d) : "v"(a), "v"(b));
    return d;
}
// weight-broadcast pk_fma: use LO (resp. HI) word of w for BOTH lanes.
__device__ __forceinline__ vf2 pk_fma_blo(vf2 w, vf2 b, vf2 c) {
    vf2 d;
    asm("v_pk_fma_f32 %0, %1, %2, %3 op_sel_hi:[0,1,1]"
        : "=v"(d) : "v"(w), "v"(b), "v"(c));
    return d;
}
__device__ __forceinline__ vf2 pk_fma_bhi(vf2 w, vf2 b, vf2 c) {
    vf2 d;
    asm("v_pk_fma_f32 %0, %1, %2, %3 op_sel:[1,0,0] op_sel_hi:[1,1,1]"
        : "=v"(d) : "v"(w), "v"(b), "v"(c));
    return d;
}

// ================= streaming level-0 kernel =================
// Thread owns output column ox = c0 + tid. Streams input rows in chunks of
// 11 (fully unrolled -> mod-11 register ring has static indices).
// RING DISCIPLINE: slot j%11 reset at START of row j (r14 correctness fix).
// r15: one-row SOFTWARE PIPELINE of the LDS reads — row j+1's 6 b128 reads
// are issued before row j's compute (ping-pong q0/q1, parity static after
// unroll), hiding ~130cy ds_read latency under ~140cy of pk-math. Math is
// bit-identical to r14.
#define L0_H 512
#define L0_HOUT 502
#define L0_HP 256
#define L0_SEG 64
#define L0_NCHUNK 7                 // ceil((SEG+10)/11)
#define ROWW 536                    // 268 staged cols x (P,Q) words
#define NQ 134                      // quads per row
#define CARRY_BASE (11 * ROWW)      // 5896
#define STREAM_WORDS (CARRY_BASE + 2 * ROWW)   // + ping-pong carry

__global__ __launch_bounds__(256)
void msssim_stream_l0(const float* __restrict__ img1,
                      const float* __restrict__ img2,
                      double* __restrict__ sums,
                      float* __restrict__ poolP, float* __restrict__ poolQ)
{
    __shared__ __align__(16) float buf[STREAM_WORDS];
    __shared__ float wred[4][2];

    const float gs[11] = {0.00102838f, 0.00759875f, 0.03600077f, 0.10936070f,
                          0.21300554f, 0.26601173f, 0.21300554f, 0.10936070f,
                          0.03600077f, 0.00759875f, 0.00102838f};

    const int tid = threadIdx.x;
    const int c0 = blockIdx.x * 256;          // strip base col
    const int oy0 = blockIdx.y * L0_SEG;      // seg base output row
    const long long plane = (long long)blockIdx.z * L0_H * L0_H;
    const long long pplane = (long long)blockIdx.z * L0_HP * L0_HP;
    const bool colok = (c0 + tid) < L0_HOUT;

    // ---- weights: h taps (parity-shifted, 12) packed in 6 vf2;
    //      v taps (symmetric, 6 distinct) broadcast in 6 vf2
    const int par = tid & 1;
    vf2 wp[6];
    #pragma unroll
    for (int jq = 0; jq < 6; ++jq) {
        const int i0 = 2 * jq, i1 = 2 * jq + 1;
        const float we0 = (i0 < 11) ? gs[i0] : 0.f;
        const float wo0 = (i0 >= 1) ? gs[i0 - 1] : 0.f;
        const float we1 = (i1 < 11) ? gs[i1] : 0.f;
        const float wo1 = (i1 >= 1) ? gs[i1 - 1] : 0.f;
        wp[jq].x = par ? wo0 : we0;
        wp[jq].y = par ? wo1 : we1;
    }
    vf2 wgv[6];
    #pragma unroll
    for (int k = 0; k < 6; ++k) { wgv[k].x = gs[k]; wgv[k].y = gs[k]; }

    // ---- staging slots: 1474 quads (11 rows x 134), 6 slots/thread
    int rowS[6], colS[6], ldsoff[6], rHS[6];
    #pragma unroll
    for (int t = 0; t < 6; ++t) {
        const int s = tid + 256 * t;
        if (s < 11 * NQ) {
            const int r = s / NQ, q = s - NQ * r;
            rowS[t] = r;
            colS[t] = c0 + 2 * q;
            ldsoff[t] = r * ROWW + q * 4;
            rHS[t] = r * L0_H;
        } else { rowS[t] = -1; colS[t] = 0; ldsoff[t] = 0; rHS[t] = 0; }
    }

    float4 pf[6];
    auto prefetch = [&](int ybase) {
        const int yH = ybase * L0_H;
        #pragma unroll
        for (int t = 0; t < 6; ++t) {
            float2 a = make_float2(0.f, 0.f), b = make_float2(0.f, 0.f);
            if (rowS[t] >= 0) {
                const int y = ybase + rowS[t];
                if (y < L0_H && colS[t] < L0_H) {
                    const long long idx = plane + yH + rHS[t] + colS[t];
                    a = *(const float2*)(img1 + idx);
                    b = *(const float2*)(img2 + idx);
                }
            }
            pf[t] = make_float4(a.x + b.x, a.x - b.x, a.y + b.y, a.y - b.y);
        }
    };
    auto stage_write = [&]() {
        #pragma unroll
        for (int t = 0; t < 6; ++t)
            if (rowS[t] >= 0) *(float4*)&buf[ldsoff[t]] = pf[t];
    };

    // prologue: chunk 0
    prefetch(oy0);
    stage_write();
    __syncthreads();

    // ---- pending register ring
    vf2 pd_pq[11], pd_sq[11];
    #pragma unroll
    for (int s = 0; s < 11; ++s) { pd_pq[s] = (vf2){0.f, 0.f}; pd_sq[s] = (vf2){0.f, 0.f}; }

    const int qb4 = (tid >> 1) * 4;
    const float C1 = 4.0e-4f, C2 = 3.6e-3f;
    float ssim_acc = 0.f, cs_acc = 0.f;

    for (int c = 0; c < L0_NCHUNK; ++c) {
        const int cs = oy0 + 11 * c;          // first input row of chunk
        const bool more = (c + 1 < L0_NCHUNK);

        if (more) prefetch(cs + 11);          // loads hide under compute

        // ---- fused pool of (P,Q) rows (pairs inside chunk + spanning)
        if (tid < 128) {
            const int px = (c0 >> 1) + tid;
            const int t4 = tid * 4;
            for (int jp = (cs & 1); jp + 1 <= 10; jp += 2) {
                const int py = (cs + jp) >> 1;
                if (py < L0_HP) {
                    const float4 v0 = *(const float4*)&buf[jp * ROWW + t4];
                    const float4 v1 = *(const float4*)&buf[(jp + 1) * ROWW + t4];
                    poolP[pplane + py * L0_HP + px] = 0.25f * (v0.x + v0.z + v1.x + v1.z);
                    poolQ[pplane + py * L0_HP + px] = 0.25f * (v0.y + v0.w + v1.y + v1.w);
                }
            }
            if (c > 0 && (cs & 1)) {          // spanning pair (cs-1, cs)
                const int py = (cs - 1) >> 1;
                if (py < L0_HP) {
                    const float4 v0 = *(const float4*)&buf[CARRY_BASE + ((c - 1) & 1) * ROWW + t4];
                    const float4 v1 = *(const float4*)&buf[t4];
                    poolP[pplane + py * L0_HP + px] = 0.25f * (v0.x + v0.z + v1.x + v1.z);
                    poolQ[pplane + py * L0_HP + px] = 0.25f * (v0.y + v0.w + v1.y + v1.w);
                }
            }
        }
        if (((cs & 1) == 0) && more && tid < NQ) {   // next chunk spans: save last row
            *(float4*)&buf[CARRY_BASE + (c & 1) * ROWW + tid * 4] =
                *(const float4*)&buf[10 * ROWW + tid * 4];
        }

        // ---- 11 unrolled rows, one-row LDS pipeline:
        //      reset slot j -> issue row j+1 reads -> h(row j) -> scatter -> emit
        float4 q0[6], q1[6];
        #pragma unroll
        for (int u = 0; u < 6; ++u) q0[u] = *(const float4*)&buf[qb4 + 4 * u];  // row 0

        #pragma unroll
        for (int j = 0; j < 11; ++j) {
            // reset the slot whose new output's first tap (k=0) is this row
            pd_pq[j] = (vf2){0.f, 0.f};
            pd_sq[j] = (vf2){0.f, 0.f};

            const float4* qc = (j & 1) ? q1 : q0;   // static after unroll
            float4*       qn = (j & 1) ? q0 : q1;
            if (j < 10) {                            // issue next row's reads early
                const int rwn = (j + 1) * ROWW + qb4;
                #pragma unroll
                for (int u = 0; u < 6; ++u) qn[u] = *(const float4*)&buf[rwn + 4 * u];
            }

            vf2 hpq = {0.f, 0.f}, hsq = {0.f, 0.f};
            #pragma unroll
            for (int u = 0; u < 6; ++u) {
                const vf2 elo = {qc[u].x, qc[u].y};
                const vf2 ehi = {qc[u].z, qc[u].w};
                const vf2 slo = pk_mul(elo, elo);
                const vf2 shi = pk_mul(ehi, ehi);
                hpq = pk_fma_blo(wp[u], elo, hpq);
                hpq = pk_fma_bhi(wp[u], ehi, hpq);
                hsq = pk_fma_blo(wp[u], slo, hsq);
                hsq = pk_fma_bhi(wp[u], shi, hsq);
            }
            #pragma unroll
            for (int k = 0; k < 11; ++k) {
                const int s = (j - k + 11) % 11;       // static
                const int m = (k <= 5) ? k : 10 - k;   // static
                pd_pq[s] = pk_fma(wgv[m], hpq, pd_pq[s]);
                pd_sq[s] = pk_fma(wgv[m], hsq, pd_sq[s]);
            }
            const int yrel = 11 * c + j;
            if (yrel >= 10) {
                const int s = (j + 1) % 11;            // static
                const int orow = yrel - 10;
                if (orow < L0_SEG && (oy0 + orow) < L0_HOUT && colok) {
                    const vf2 musq = pk_mul(pd_pq[s], pd_pq[s]);  // (cP^2,cQ^2)
                    const float sP = pd_sq[s].x - musq.x;
                    const float sQ = pd_sq[s].y - musq.y;
                    const float v1 = 0.5f * (sP - sQ) + C2;
                    const float v2 = 0.5f * (sP + sQ) + C2;
                    const float num1 = 0.5f * (musq.x - musq.y) + C1;
                    const float den1 = 0.5f * (musq.x + musq.y) + C1;
                    cs_acc += v1 * __builtin_amdgcn_rcpf(v2);
                    ssim_acc += num1 * v1 * __builtin_amdgcn_rcpf(den1 * v2);
                }
                // slot reset happens at start of next row
            }
        }

        __syncthreads();              // all buf reads done
        if (more) stage_write();      // write chunk c+1
        __syncthreads();              // buf ready
    }

    // ---- block reduction + atomics (level 0)
    #pragma unroll
    for (int off = 32; off > 0; off >>= 1) {
        ssim_acc += __shfl_down(ssim_acc, off);
        cs_acc   += __shfl_down(cs_acc, off);
    }
    const int wave = tid >> 6;
    if ((tid & 63) == 0) { wred[wave][0] = ssim_acc; wred[wave][1] = cs_acc; }
    __syncthreads();
    if (tid == 0) {
        atomicAdd(&sums[0], (double)(wred[0][0] + wred[1][0] + wred[2][0] + wred[3][0]));
        atomicAdd(&sums[5], (double)(wred[0][1] + wred[1][1] + wred[2][1] + wred[3][1]));
    }
}

// ================= phase kernel for levels 1-4 (r14 verbatim) =================
#define TILE 32
#define IN_DIM 42
#define SCP 21
#define HALO 10
#define STAGE_WORDS (IN_DIM * SCP * 4)
#define SH 340
#define HB STAGE_WORDS
#define SMEM_WORDS (HB + 16 * SH)

__global__ __launch_bounds__(256)
void msssim_level_kernel(const float* __restrict__ src1,
                         const float* __restrict__ src2,
                         int H, int level, int tiles_per_seg, int pq_input,
                         double* __restrict__ sums,
                         float* __restrict__ pool1, float* __restrict__ pool2)
{
    __shared__ __align__(16) float smem[SMEM_WORDS];
    __shared__ float wred[4][2];

    const float g[11] = {0.00102838f, 0.00759875f, 0.03600077f, 0.10936070f,
                         0.21300554f, 0.26601173f, 0.21300554f, 0.10936070f,
                         0.03600077f, 0.00759875f, 0.00102838f};
    vf2 wg[11];
    #pragma unroll
    for (int k = 0; k < 11; ++k) { wg[k].x = g[k]; wg[k].y = g[k]; }

    const int tid = threadIdx.x;
    const int Hout = H - HALO;
    const int ntiles = (Hout + TILE - 1) / TILE;
    const int tstart = blockIdx.y * tiles_per_seg;
    const int tend = min(ntiles, tstart + tiles_per_seg);
    const int ox0 = blockIdx.x * TILE;
    const int Hp = H >> 1;
    const long long base = (long long)blockIdx.z * H * H;

    int rHS[4], rS[4], xS[4];
    #pragma unroll
    for (int t4 = 0; t4 < 4; ++t4) {
        const int s = tid + 256 * t4;
        if (s < IN_DIM * SCP) {
            const int r = s / SCP, cp = s - r * SCP;
            rS[t4] = r; rHS[t4] = r * H; xS[t4] = ox0 + 2 * cp;
        } else { rS[t4] = -1; rHS[t4] = 0; xS[t4] = 0; }
    }

    auto load_slot = [&](int t4, int ybase) -> float4 {
        float2 a = make_float2(0.f, 0.f), b = make_float2(0.f, 0.f);
        if (rS[t4] >= 0) {
            const int y = ybase + rS[t4], x = xS[t4];
            if (y < H && x < H) {
                const long long idx = base + (long long)ybase * H + rHS[t4] + x;
                a = *(const float2*)(src1 + idx);
                b = *(const float2*)(src2 + idx);
            }
        }
        if (pq_input) return make_float4(a.x, b.x, a.y, b.y);
        return make_float4(a.x + b.x, a.x - b.x, a.y + b.y, a.y - b.y);
    };

    float4 pref[4];
    {
        #pragma unroll
        for (int t4 = 0; t4 < 4; ++t4) pref[t4] = load_slot(t4, tstart * TILE);
        #pragma unroll
        for (int t4 = 0; t4 < 4; ++t4)
            if (rS[t4] >= 0) *(float4*)&smem[(tid + 256 * t4) * 4] = pref[t4];
    }
    __syncthreads();

    float ssim_acc = 0.f, cs_acc = 0.f;

    for (int tt = tstart; tt < tend; ++tt) {
        const int ty0 = tt * TILE;
        const bool more = (tt + 1 < tend);

        if (more) {
            #pragma unroll
            for (int t4 = 0; t4 < 4; ++t4) pref[t4] = load_slot(t4, ty0 + TILE);
        }

        if (pool1 != nullptr) {
            const int pr = tid >> 4, pc = tid & 15;
            const int py = (ty0 >> 1) + pr, px = (ox0 >> 1) + pc;
            if (py < Hp && px < Hp) {
                const float4 v0 = *(const float4*)&smem[(2 * pr * SCP + pc) * 4];
                const float4 v1 = *(const float4*)&smem[((2 * pr + 1) * SCP + pc) * 4];
                const long long ob = (long long)blockIdx.z * Hp * Hp + (long long)py * Hp + px;
                pool1[ob] = 0.25f * (v0.x + v0.z + v1.x + v1.z);
                pool2[ob] = 0.25f * (v0.y + v0.w + v1.y + v1.w);
            }
        }

        float4 hA[3], hBv[3];
        #pragma unroll
        for (int t = 0; t < 3; ++t) {
            const int p = tid + 256 * t;
            if (p < IN_DIM * 16) {
                const int r = p >> 4, m = p & 15;
                vf2 Apq = {0.f, 0.f}, Asq = {0.f, 0.f};
                vf2 Bpq = {0.f, 0.f}, Bsq = {0.f, 0.f};
                #pragma unroll
                for (int jj = 0; jj < 6; ++jj) {
                    const float4 v = *(const float4*)&smem[(r * SCP + m + jj) * 4];
                    const vf2 lo = {v.x, v.y};
                    const vf2 hi = {v.z, v.w};
                    const vf2 losq = pk_mul(lo, lo);
                    const vf2 hisq = pk_mul(hi, hi);
                    Apq = pk_fma(wg[2 * jj], lo, Apq);
                    Asq = pk_fma(wg[2 * jj], losq, Asq);
                    if (jj >= 1) {
                        Bpq = pk_fma(wg[2 * jj - 1], lo, Bpq);
                        Bsq = pk_fma(wg[2 * jj - 1], losq, Bsq);
                    }
                    if (jj <= 4) {
                        Apq = pk_fma(wg[2 * jj + 1], hi, Apq);
                        Asq = pk_fma(wg[2 * jj + 1], hisq, Asq);
                    }
                    Bpq = pk_fma(wg[2 * jj], hi, Bpq);
                    Bsq = pk_fma(wg[2 * jj], hisq, Bsq);
                }
                hA[t]  = make_float4(Apq.x, Apq.y, Asq.x, Asq.y);
                hBv[t] = make_float4(Bpq.x, Bpq.y, Bsq.x, Bsq.y);
            }
        }
        __syncthreads();

        #pragma unroll
        for (int t = 0; t < 3; ++t) {
            const int p = tid + 256 * t;
            if (p < IN_DIM * 16) {
                const int r = p >> 4, m = p & 15;
                const int hb = HB + m * SH + r * 8;
                *(float4*)&smem[hb]     = hA[t];
                *(float4*)&smem[hb + 4] = hBv[t];
            }
        }
        if (more) {
            #pragma unroll
            for (int t4 = 0; t4 < 4; ++t4)
                if (rS[t4] >= 0) *(float4*)&smem[(tid + 256 * t4) * 4] = pref[t4];
        }
        __syncthreads();

        const int tx = tid & 31, rg = tid >> 5;
        const int r0 = rg * 4;
        const int m = tx >> 1, par = tx & 1;
        const int hb = HB + m * SH + par * 4;

        vf2 accPQ[4], accSQ[4];
        #pragma unroll
        for (int o = 0; o < 4; ++o) {
            accPQ[o] = (vf2){0.f, 0.f};
            accSQ[o] = (vf2){0.f, 0.f};
        }
        #pragma unroll
        for (int i = 0; i < 14; ++i) {
            const float4 h4 = *(const float4*)&smem[hb + (r0 + i) * 8];
            const vf2 ppq = {h4.x, h4.y};
            const vf2 psq = {h4.z, h4.w};
            #pragma unroll
            for (int o = 0; o < 4; ++o) {
                const int k = i - o;
                if (k >= 0 && k <= 10) {
                    accPQ[o] = pk_fma(wg[k], ppq, accPQ[o]);
                    accSQ[o] = pk_fma(wg[k], psq, accSQ[o]);
                }
            }
        }

        const float C1 = 4.0e-4f;
        const float C2 = 3.6e-3f;
        const int ox = ox0 + tx;
        #pragma unroll
        for (int o = 0; o < 4; ++o) {
            const int oy = ty0 + r0 + o;
            if (oy < Hout && ox < Hout) {
                const vf2 musq = pk_mul(accPQ[o], accPQ[o]);
                const float sP = accSQ[o].x - musq.x;
                const float sQ = accSQ[o].y - musq.y;
                const float v1 = 0.5f * (sP - sQ) + C2;
                const float v2 = 0.5f * (sP + sQ) + C2;
                const float num1 = 0.5f * (musq.x - musq.y) + C1;
                const float den1 = 0.5f * (musq.x + musq.y) + C1;
                cs_acc += v1 * __builtin_amdgcn_rcpf(v2);
                ssim_acc += num1 * v1 * __builtin_amdgcn_rcpf(den1 * v2);
            }
        }
    }

    #pragma unroll
    for (int off = 32; off > 0; off >>= 1) {
        ssim_acc += __shfl_down(ssim_acc, off);
        cs_acc   += __shfl_down(cs_acc, off);
    }
    const int wave = tid >> 6;
    if ((tid & 63) == 0) { wred[wave][0] = ssim_acc; wred[wave][1] = cs_acc; }
    __syncthreads();
    if (tid == 0) {
        const float s = wred[0][0] + wred[1][0] + wred[2][0] + wred[3][0];
        const float c = wred[0][1] + wred[1][1] + wred[2][1] + wred[3][1];
        atomicAdd(&sums[level],     (double)s);
        atomicAdd(&sums[5 + level], (double)c);
    }
}

// -------------------- final combine --------------------
__global__ void msssim_final_kernel(const double* __restrict__ sums,
                                    float* __restrict__ out)
{
    if (threadIdx.x == 0 && blockIdx.x == 0) {
        const double W[5] = {0.0448, 0.2856, 0.3001, 0.2363, 0.1333};
        const int Houts[5] = {502, 246, 118, 54, 22};
        double mssim[5], mcs[5];
        for (int l = 0; l < 5; ++l) {
            const double cnt = 48.0 * (double)Houts[l] * (double)Houts[l];
            mssim[l] = (sums[l]     / cnt + 1.0) * 0.5;
            mcs[l]   = (sums[5 + l] / cnt + 1.0) * 0.5;
        }
        const double p2 = pow(mssim[4], W[4]);
        double prod = 1.0;
        for (int l = 0; l < 4; ++l) prod *= pow(mcs[l], W[l]) * p2;
        out[0] = (float)(1.0 - prod);
    }
}

// -------------------- launch --------------------
extern "C" void kernel_launch(void* const* d_in, const int* in_sizes, int n_in,
                              void* d_out, int out_size, void* d_ws, size_t ws_size,
                              hipStream_t stream)
{
    const float* img1 = (const float*)d_in[0];
    const float* img2 = (const float*)d_in[1];
    float* out = (float*)d_out;
    (void)in_sizes; (void)n_in; (void)out_size; (void)ws_size;

    char* ws = (char*)d_ws;
    double* sums = (double*)ws;                      // 10 doubles
    float* X1 = (float*)(ws + 256);                  // P planes (L1 input)
    float* X2 = X1 + 3145728;                        // Q planes
    float* Y1 = X2 + 3145728;
    float* Y2 = Y1 + 786432;

    hipMemsetAsync(sums, 0, 10 * sizeof(double), stream);

    // level 0: streaming kernel, r10-proven grid (2 strips x 8 segs x 48 = 768)
    hipLaunchKernelGGL(msssim_stream_l0, dim3(2, 8, 48), dim3(256), 0, stream,
                       img1, img2, sums, X1, X2);

    // levels 1-4: phase kernel, r10-proven seg config
    auto launch_level = [&](const float* a, const float* b, int H, int level,
                            int segs, float* pa, float* pb) {
        const int Hout = H - HALO;
        const int strips = (Hout + TILE - 1) / TILE;
        const int ntiles = (Hout + TILE - 1) / TILE;
        const int tps = (ntiles + segs - 1) / segs;
        dim3 grid(strips, segs, 48);
        hipLaunchKernelGGL(msssim_level_kernel, grid, dim3(256), 0, stream,
                           a, b, H, level, tps, 1, sums, pa, pb);
    };

    launch_level(X1, X2, 256, 1, 2, Y1, Y2);          // level 1 -> (128)
    launch_level(Y1, Y2, 128, 2, 4, X1, X2);          // level 2 -> (64)
    launch_level(X1, X2, 64, 3, 2, Y1, Y2);           // level 3 -> (32)
    launch_level(Y1, Y2, 32, 4, 1, nullptr, nullptr); // level 4

    hipLaunchKernelGGL(msssim_final_kernel, dim3(1), dim3(64), 0, stream, sums, out);
}

// Round 16
// 139.818 us; speedup vs baseline: 1.0860x; 1.0860x over previous
//
#include <hip/hip_runtime.h>
#include <math.h>

typedef float vf2 __attribute__((ext_vector_type(2)));

// ---------------- packed dual-fp32 helpers (VOP3P) ----------------
__device__ __forceinline__ vf2 pk_fma(vf2 a, vf2 b, vf2 c) {
    vf2 d;
    asm("v_pk_fma_f32 %0, %1, %2, %3" : "=v"(d) : "v"(a), "v"(b), "v"(c));
    return d;
}
__device__ __forceinline__ vf2 pk_mul(vf2 a, vf2 b) {
    vf2 d;
    asm("v_pk_mul_f32 %0, %1, %2" : "=v"(d) : "v"(a), "v"(b));
    return d;
}
// weight-broadcast pk_fma: use LO (resp. HI) word of w for BOTH lanes.
__device__ __forceinline__ vf2 pk_fma_blo(vf2 w, vf2 b, vf2 c) {
    vf2 d;
    asm("v_pk_fma_f32 %0, %1, %2, %3 op_sel_hi:[0,1,1]"
        : "=v"(d) : "v"(w), "v"(b), "v"(c));
    return d;
}
__device__ __forceinline__ vf2 pk_fma_bhi(vf2 w, vf2 b, vf2 c) {
    vf2 d;
    asm("v_pk_fma_f32 %0, %1, %2, %3 op_sel:[1,0,0] op_sel_hi:[1,1,1]"
        : "=v"(d) : "v"(w), "v"(b), "v"(c));
    return d;
}

// ================= streaming level-0 kernel =================
// Thread owns output column ox = c0 + tid. Streams input rows in chunks of
// 11 (fully unrolled -> mod-11 register ring has static indices).
// RING DISCIPLINE: slot j%11 reset at START of row j (r14 correctness fix).
// r16: LDS DOUBLE-BUFFER — chunk c computes from buf[c&1] while staging
// writes buf[(c+1)&1]; ONE barrier per chunk instead of two (the reads-done
// barrier existed only because staging overwrote the live buffer). Carry
// rows stay ping-pong (write slot c&1, read slot (c-1)&1 — disjoint).
// Math bit-identical to r14; VGPR unchanged.
#define L0_H 512
#define L0_HOUT 502
#define L0_HP 256
#define L0_SEG 64
#define L0_NCHUNK 7                 // ceil((SEG+10)/11)
#define ROWW 536                    // 268 staged cols x (P,Q) words
#define NQ 134                      // quads per row
#define BUF_WORDS (11 * ROWW)       // 5896 per buffer
#define CARRY0 (2 * BUF_WORDS)      // 11792
#define STREAM_WORDS (CARRY0 + 2 * ROWW)   // 12864 words = 51456 B -> 3 blocks/CU

__global__ __launch_bounds__(256)
void msssim_stream_l0(const float* __restrict__ img1,
                      const float* __restrict__ img2,
                      double* __restrict__ sums,
                      float* __restrict__ poolP, float* __restrict__ poolQ)
{
    __shared__ __align__(16) float buf[STREAM_WORDS];
    __shared__ float wred[4][2];

    const float gs[11] = {0.00102838f, 0.00759875f, 0.03600077f, 0.10936070f,
                          0.21300554f, 0.26601173f, 0.21300554f, 0.10936070f,
                          0.03600077f, 0.00759875f, 0.00102838f};

    const int tid = threadIdx.x;
    const int c0 = blockIdx.x * 256;          // strip base col
    const int oy0 = blockIdx.y * L0_SEG;      // seg base output row
    const long long plane = (long long)blockIdx.z * L0_H * L0_H;
    const long long pplane = (long long)blockIdx.z * L0_HP * L0_HP;
    const bool colok = (c0 + tid) < L0_HOUT;

    // ---- weights: h taps (parity-shifted, 12) packed in 6 vf2;
    //      v taps (symmetric, 6 distinct) broadcast in 6 vf2
    const int par = tid & 1;
    vf2 wp[6];
    #pragma unroll
    for (int jq = 0; jq < 6; ++jq) {
        const int i0 = 2 * jq, i1 = 2 * jq + 1;
        const float we0 = (i0 < 11) ? gs[i0] : 0.f;
        const float wo0 = (i0 >= 1) ? gs[i0 - 1] : 0.f;
        const float we1 = (i1 < 11) ? gs[i1] : 0.f;
        const float wo1 = (i1 >= 1) ? gs[i1 - 1] : 0.f;
        wp[jq].x = par ? wo0 : we0;
        wp[jq].y = par ? wo1 : we1;
    }
    vf2 wgv[6];
    #pragma unroll
    for (int k = 0; k < 6; ++k) { wgv[k].x = gs[k]; wgv[k].y = gs[k]; }

    // ---- staging slots: 1474 quads (11 rows x 134), 6 slots/thread
    int rowS[6], colS[6], ldsoff[6], rHS[6];
    #pragma unroll
    for (int t = 0; t < 6; ++t) {
        const int s = tid + 256 * t;
        if (s < 11 * NQ) {
            const int r = s / NQ, q = s - NQ * r;
            rowS[t] = r;
            colS[t] = c0 + 2 * q;
            ldsoff[t] = r * ROWW + q * 4;
            rHS[t] = r * L0_H;
        } else { rowS[t] = -1; colS[t] = 0; ldsoff[t] = 0; rHS[t] = 0; }
    }

    float4 pf[6];
    auto prefetch = [&](int ybase) {
        const int yH = ybase * L0_H;
        #pragma unroll
        for (int t = 0; t < 6; ++t) {
            float2 a = make_float2(0.f, 0.f), b = make_float2(0.f, 0.f);
            if (rowS[t] >= 0) {
                const int y = ybase + rowS[t];
                if (y < L0_H && colS[t] < L0_H) {
                    const long long idx = plane + yH + rHS[t] + colS[t];
                    a = *(const float2*)(img1 + idx);
                    b = *(const float2*)(img2 + idx);
                }
            }
            pf[t] = make_float4(a.x + b.x, a.x - b.x, a.y + b.y, a.y - b.y);
        }
    };
    auto stage_write = [&](int base) {
        #pragma unroll
        for (int t = 0; t < 6; ++t)
            if (rowS[t] >= 0) *(float4*)&buf[base + ldsoff[t]] = pf[t];
    };

    // prologue: chunk 0 into buffer 0
    prefetch(oy0);
    stage_write(0);
    __syncthreads();

    // ---- pending register ring
    vf2 pd_pq[11], pd_sq[11];
    #pragma unroll
    for (int s = 0; s < 11; ++s) { pd_pq[s] = (vf2){0.f, 0.f}; pd_sq[s] = (vf2){0.f, 0.f}; }

    const int qb4 = (tid >> 1) * 4;
    const float C1 = 4.0e-4f, C2 = 3.6e-3f;
    float ssim_acc = 0.f, cs_acc = 0.f;

    for (int c = 0; c < L0_NCHUNK; ++c) {
        const int cs = oy0 + 11 * c;              // first input row of chunk
        const bool more = (c + 1 < L0_NCHUNK);
        const int cb = (c & 1) * BUF_WORDS;       // current buffer base
        const int nb = ((c + 1) & 1) * BUF_WORDS; // next buffer base

        if (more) prefetch(cs + 11);              // loads hide under compute

        // ---- fused pool of (P,Q) rows (pairs inside chunk + spanning)
        if (tid < 128) {
            const int px = (c0 >> 1) + tid;
            const int t4 = tid * 4;
            for (int jp = (cs & 1); jp + 1 <= 10; jp += 2) {
                const int py = (cs + jp) >> 1;
                if (py < L0_HP) {
                    const float4 v0 = *(const float4*)&buf[cb + jp * ROWW + t4];
                    const float4 v1 = *(const float4*)&buf[cb + (jp + 1) * ROWW + t4];
                    poolP[pplane + py * L0_HP + px] = 0.25f * (v0.x + v0.z + v1.x + v1.z);
                    poolQ[pplane + py * L0_HP + px] = 0.25f * (v0.y + v0.w + v1.y + v1.w);
                }
            }
            if (c > 0 && (cs & 1)) {              // spanning pair (cs-1, cs)
                const int py = (cs - 1) >> 1;
                if (py < L0_HP) {
                    const float4 v0 = *(const float4*)&buf[CARRY0 + ((c - 1) & 1) * ROWW + t4];
                    const float4 v1 = *(const float4*)&buf[cb + t4];
                    poolP[pplane + py * L0_HP + px] = 0.25f * (v0.x + v0.z + v1.x + v1.z);
                    poolQ[pplane + py * L0_HP + px] = 0.25f * (v0.y + v0.w + v1.y + v1.w);
                }
            }
        }
        if (((cs & 1) == 0) && more && tid < NQ) {   // next chunk spans: save last row
            *(float4*)&buf[CARRY0 + (c & 1) * ROWW + tid * 4] =
                *(const float4*)&buf[cb + 10 * ROWW + tid * 4];
        }

        // ---- 11 unrolled rows: reset slot j -> h -> scatter -> emit
        #pragma unroll
        for (int j = 0; j < 11; ++j) {
            pd_pq[j] = (vf2){0.f, 0.f};
            pd_sq[j] = (vf2){0.f, 0.f};

            float4 q[6];
            const int rw = cb + j * ROWW + qb4;
            #pragma unroll
            for (int u = 0; u < 6; ++u) q[u] = *(const float4*)&buf[rw + 4 * u];

            vf2 hpq = {0.f, 0.f}, hsq = {0.f, 0.f};
            #pragma unroll
            for (int u = 0; u < 6; ++u) {
                const vf2 elo = {q[u].x, q[u].y};
                const vf2 ehi = {q[u].z, q[u].w};
                const vf2 slo = pk_mul(elo, elo);
                const vf2 shi = pk_mul(ehi, ehi);
                hpq = pk_fma_blo(wp[u], elo, hpq);
                hpq = pk_fma_bhi(wp[u], ehi, hpq);
                hsq = pk_fma_blo(wp[u], slo, hsq);
                hsq = pk_fma_bhi(wp[u], shi, hsq);
            }
            #pragma unroll
            for (int k = 0; k < 11; ++k) {
                const int s = (j - k + 11) % 11;       // static
                const int m = (k <= 5) ? k : 10 - k;   // static
                pd_pq[s] = pk_fma(wgv[m], hpq, pd_pq[s]);
                pd_sq[s] = pk_fma(wgv[m], hsq, pd_sq[s]);
            }
            const int yrel = 11 * c + j;
            if (yrel >= 10) {
                const int s = (j + 1) % 11;            // static
                const int orow = yrel - 10;
                if (orow < L0_SEG && (oy0 + orow) < L0_HOUT && colok) {
                    const vf2 musq = pk_mul(pd_pq[s], pd_pq[s]);  // (cP^2,cQ^2)
                    const float sP = pd_sq[s].x - musq.x;
                    const float sQ = pd_sq[s].y - musq.y;
                    const float v1 = 0.5f * (sP - sQ) + C2;
                    const float v2 = 0.5f * (sP + sQ) + C2;
                    const float num1 = 0.5f * (musq.x - musq.y) + C1;
                    const float den1 = 0.5f * (musq.x + musq.y) + C1;
                    cs_acc += v1 * __builtin_amdgcn_rcpf(v2);
                    ssim_acc += num1 * v1 * __builtin_amdgcn_rcpf(den1 * v2);
                }
                // slot reset happens at start of next row
            }
        }

        // ---- stage chunk c+1 into the OTHER buffer, then ONE barrier
        if (more) stage_write(nb);
        __syncthreads();
    }

    // ---- block reduction + atomics (level 0)
    #pragma unroll
    for (int off = 32; off > 0; off >>= 1) {
        ssim_acc += __shfl_down(ssim_acc, off);
        cs_acc   += __shfl_down(cs_acc, off);
    }
    const int wave = tid >> 6;
    if ((tid & 63) == 0) { wred[wave][0] = ssim_acc; wred[wave][1] = cs_acc; }
    __syncthreads();
    if (tid == 0) {
        atomicAdd(&sums[0], (double)(wred[0][0] + wred[1][0] + wred[2][0] + wred[3][0]));
        atomicAdd(&sums[5], (double)(wred[0][1] + wred[1][1] + wred[2][1] + wred[3][1]));
    }
}

// ================= phase kernel for levels 1-4 (r14 verbatim) =================
#define TILE 32
#define IN_DIM 42
#define SCP 21
#define HALO 10
#define STAGE_WORDS (IN_DIM * SCP * 4)
#define SH 340
#define HB STAGE_WORDS
#define SMEM_WORDS (HB + 16 * SH)

__global__ __launch_bounds__(256)
void msssim_level_kernel(const float* __restrict__ src1,
                         const float* __restrict__ src2,
                         int H, int level, int tiles_per_seg, int pq_input,
                         double* __restrict__ sums,
                         float* __restrict__ pool1, float* __restrict__ pool2)
{
    __shared__ __align__(16) float smem[SMEM_WORDS];
    __shared__ float wred[4][2];

    const float g[11] = {0.00102838f, 0.00759875f, 0.03600077f, 0.10936070f,
                         0.21300554f, 0.26601173f, 0.21300554f, 0.10936070f,
                         0.03600077f, 0.00759875f, 0.00102838f};
    vf2 wg[11];
    #pragma unroll
    for (int k = 0; k < 11; ++k) { wg[k].x = g[k]; wg[k].y = g[k]; }

    const int tid = threadIdx.x;
    const int Hout = H - HALO;
    const int ntiles = (Hout + TILE - 1) / TILE;
    const int tstart = blockIdx.y * tiles_per_seg;
    const int tend = min(ntiles, tstart + tiles_per_seg);
    const int ox0 = blockIdx.x * TILE;
    const int Hp = H >> 1;
    const long long base = (long long)blockIdx.z * H * H;

    int rHS[4], rS[4], xS[4];
    #pragma unroll
    for (int t4 = 0; t4 < 4; ++t4) {
        const int s = tid + 256 * t4;
        if (s < IN_DIM * SCP) {
            const int r = s / SCP, cp = s - r * SCP;
            rS[t4] = r; rHS[t4] = r * H; xS[t4] = ox0 + 2 * cp;
        } else { rS[t4] = -1; rHS[t4] = 0; xS[t4] = 0; }
    }

    auto load_slot = [&](int t4, int ybase) -> float4 {
        float2 a = make_float2(0.f, 0.f), b = make_float2(0.f, 0.f);
        if (rS[t4] >= 0) {
            const int y = ybase + rS[t4], x = xS[t4];
            if (y < H && x < H) {
                const long long idx = base + (long long)ybase * H + rHS[t4] + x;
                a = *(const float2*)(src1 + idx);
                b = *(const float2*)(src2 + idx);
            }
        }
        if (pq_input) return make_float4(a.x, b.x, a.y, b.y);
        return make_float4(a.x + b.x, a.x - b.x, a.y + b.y, a.y - b.y);
    };

    float4 pref[4];
    {
        #pragma unroll
        for (int t4 = 0; t4 < 4; ++t4) pref[t4] = load_slot(t4, tstart * TILE);
        #pragma unroll
        for (int t4 = 0; t4 < 4; ++t4)
            if (rS[t4] >= 0) *(float4*)&smem[(tid + 256 * t4) * 4] = pref[t4];
    }
    __syncthreads();

    float ssim_acc = 0.f, cs_acc = 0.f;

    for (int tt = tstart; tt < tend; ++tt) {
        const int ty0 = tt * TILE;
        const bool more = (tt + 1 < tend);

        if (more) {
            #pragma unroll
            for (int t4 = 0; t4 < 4; ++t4) pref[t4] = load_slot(t4, ty0 + TILE);
        }

        if (pool1 != nullptr) {
            const int pr = tid >> 4, pc = tid & 15;
            const int py = (ty0 >> 1) + pr, px = (ox0 >> 1) + pc;
            if (py < Hp && px < Hp) {
                const float4 v0 = *(const float4*)&smem[(2 * pr * SCP + pc) * 4];
                const float4 v1 = *(const float4*)&smem[((2 * pr + 1) * SCP + pc) * 4];
                const long long ob = (long long)blockIdx.z * Hp * Hp + (long long)py * Hp + px;
                pool1[ob] = 0.25f * (v0.x + v0.z + v1.x + v1.z);
                pool2[ob] = 0.25f * (v0.y + v0.w + v1.y + v1.w);
            }
        }

        float4 hA[3], hBv[3];
        #pragma unroll
        for (int t = 0; t < 3; ++t) {
            const int p = tid + 256 * t;
            if (p < IN_DIM * 16) {
                const int r = p >> 4, m = p & 15;
                vf2 Apq = {0.f, 0.f}, Asq = {0.f, 0.f};
                vf2 Bpq = {0.f, 0.f}, Bsq = {0.f, 0.f};
                #pragma unroll
                for (int jj = 0; jj < 6; ++jj) {
                    const float4 v = *(const float4*)&smem[(r * SCP + m + jj) * 4];
                    const vf2 lo = {v.x, v.y};
                    const vf2 hi = {v.z, v.w};
                    const vf2 losq = pk_mul(lo, lo);
                    const vf2 hisq = pk_mul(hi, hi);
                    Apq = pk_fma(wg[2 * jj], lo, Apq);
                    Asq = pk_fma(wg[2 * jj], losq, Asq);
                    if (jj >= 1) {
                        Bpq = pk_fma(wg[2 * jj - 1], lo, Bpq);
                        Bsq = pk_fma(wg[2 * jj - 1], losq, Bsq);
                    }
                    if (jj <= 4) {
                        Apq = pk_fma(wg[2 * jj + 1], hi, Apq);
                        Asq = pk_fma(wg[2 * jj + 1], hisq, Asq);
                    }
                    Bpq = pk_fma(wg[2 * jj], hi, Bpq);
                    Bsq = pk_fma(wg[2 * jj], hisq, Bsq);
                }
                hA[t]  = make_float4(Apq.x, Apq.y, Asq.x, Asq.y);
                hBv[t] = make_float4(Bpq.x, Bpq.y, Bsq.x, Bsq.y);
            }
        }
        __syncthreads();

        #pragma unroll
        for (int t = 0; t < 3; ++t) {
            const int p = tid + 256 * t;
            if (p < IN_DIM * 16) {
                const int r = p >> 4, m = p & 15;
                const int hb = HB + m * SH + r * 8;
                *(float4*)&smem[hb]     = hA[t];
                *(float4*)&smem[hb + 4] = hBv[t];
            }
        }
        if (more) {
            #pragma unroll
            for (int t4 = 0; t4 < 4; ++t4)
                if (rS[t4] >= 0) *(float4*)&smem[(tid + 256 * t4) * 4] = pref[t4];
        }
        __syncthreads();

        const int tx = tid & 31, rg = tid >> 5;
        const int r0 = rg * 4;
        const int m = tx >> 1, par = tx & 1;
        const int hb = HB + m * SH + par * 4;

        vf2 accPQ[4], accSQ[4];
        #pragma unroll
        for (int o = 0; o < 4; ++o) {
            accPQ[o] = (vf2){0.f, 0.f};
            accSQ[o] = (vf2){0.f, 0.f};
        }
        #pragma unroll
        for (int i = 0; i < 14; ++i) {
            const float4 h4 = *(const float4*)&smem[hb + (r0 + i) * 8];
            const vf2 ppq = {h4.x, h4.y};
            const vf2 psq = {h4.z, h4.w};
            #pragma unroll
            for (int o = 0; o < 4; ++o) {
                const int k = i - o;
                if (k >= 0 && k <= 10) {
                    accPQ[o] = pk_fma(wg[k], ppq, accPQ[o]);
                    accSQ[o] = pk_fma(wg[k], psq, accSQ[o]);
                }
            }
        }

        const float C1 = 4.0e-4f;
        const float C2 = 3.6e-3f;
        const int ox = ox0 + tx;
        #pragma unroll
        for (int o = 0; o < 4; ++o) {
            const int oy = ty0 + r0 + o;
            if (oy < Hout && ox < Hout) {
                const vf2 musq = pk_mul(accPQ[o], accPQ[o]);
                const float sP = accSQ[o].x - musq.x;
                const float sQ = accSQ[o].y - musq.y;
                const float v1 = 0.5f * (sP - sQ) + C2;
                const float v2 = 0.5f * (sP + sQ) + C2;
                const float num1 = 0.5f * (musq.x - musq.y) + C1;
                const float den1 = 0.5f * (musq.x + musq.y) + C1;
                cs_acc += v1 * __builtin_amdgcn_rcpf(v2);
                ssim_acc += num1 * v1 * __builtin_amdgcn_rcpf(den1 * v2);
            }
        }
    }

    #pragma unroll
    for (int off = 32; off > 0; off >>= 1) {
        ssim_acc += __shfl_down(ssim_acc, off);
        cs_acc   += __shfl_down(cs_acc, off);
    }
    const int wave = tid >> 6;
    if ((tid & 63) == 0) { wred[wave][0] = ssim_acc; wred[wave][1] = cs_acc; }
    __syncthreads();
    if (tid == 0) {
        const float s = wred[0][0] + wred[1][0] + wred[2][0] + wred[3][0];
        const float c = wred[0][1] + wred[1][1] + wred[2][1] + wred[3][1];
        atomicAdd(&sums[level],     (double)s);
        atomicAdd(&sums[5 + level], (double)c);
    }
}

// -------------------- final combine --------------------
__global__ void msssim_final_kernel(const double* __restrict__ sums,
                                    float* __restrict__ out)
{
    if (threadIdx.x == 0 && blockIdx.x == 0) {
        const double W[5] = {0.0448, 0.2856, 0.3001, 0.2363, 0.1333};
        const int Houts[5] = {502, 246, 118, 54, 22};
        double mssim[5], mcs[5];
        for (int l = 0; l < 5; ++l) {
            const double cnt = 48.0 * (double)Houts[l] * (double)Houts[l];
            mssim[l] = (sums[l]     / cnt + 1.0) * 0.5;
            mcs[l]   = (sums[5 + l] / cnt + 1.0) * 0.5;
        }
        const double p2 = pow(mssim[4], W[4]);
        double prod = 1.0;
        for (int l = 0; l < 4; ++l) prod *= pow(mcs[l], W[l]) * p2;
        out[0] = (float)(1.0 - prod);
    }
}

// -------------------- launch --------------------
extern "C" void kernel_launch(void* const* d_in, const int* in_sizes, int n_in,
                              void* d_out, int out_size, void* d_ws, size_t ws_size,
                              hipStream_t stream)
{
    const float* img1 = (const float*)d_in[0];
    const float* img2 = (const float*)d_in[1];
    float* out = (float*)d_out;
    (void)in_sizes; (void)n_in; (void)out_size; (void)ws_size;

    char* ws = (char*)d_ws;
    double* sums = (double*)ws;                      // 10 doubles
    float* X1 = (float*)(ws + 256);                  // P planes (L1 input)
    float* X2 = X1 + 3145728;                        // Q planes
    float* Y1 = X2 + 3145728;
    float* Y2 = Y1 + 786432;

    hipMemsetAsync(sums, 0, 10 * sizeof(double), stream);

    // level 0: streaming kernel, r10-proven grid (2 strips x 8 segs x 48 = 768)
    hipLaunchKernelGGL(msssim_stream_l0, dim3(2, 8, 48), dim3(256), 0, stream,
                       img1, img2, sums, X1, X2);

    // levels 1-4: phase kernel, r10-proven seg config
    auto launch_level = [&](const float* a, const float* b, int H, int level,
                            int segs, float* pa, float* pb) {
        const int Hout = H - HALO;
        const int strips = (Hout + TILE - 1) / TILE;
        const int ntiles = (Hout + TILE - 1) / TILE;
        const int tps = (ntiles + segs - 1) / segs;
        dim3 grid(strips, segs, 48);
        hipLaunchKernelGGL(msssim_level_kernel, grid, dim3(256), 0, stream,
                           a, b, H, level, tps, 1, sums, pa, pb);
    };

    launch_level(X1, X2, 256, 1, 2, Y1, Y2);          // level 1 -> (128)
    launch_level(Y1, Y2, 128, 2, 4, X1, X2);          // level 2 -> (64)
    launch_level(X1, X2, 64, 3, 2, Y1, Y2);           // level 3 -> (32)
    launch_level(Y1, Y2, 32, 4, 1, nullptr, nullptr); // level 4

    hipLaunchKernelGGL(msssim_final_kernel, dim3(1), dim3(64), 0, stream, sums, out);
}

// Round 17
// 131.812 us; speedup vs baseline: 1.1520x; 1.0607x over previous
//
#include <hip/hip_runtime.h>
#include <math.h>

typedef float vf2 __attribute__((ext_vector_type(2)));

// ---------------- packed dual-fp32 helpers (VOP3P) ----------------
__device__ __forceinline__ vf2 pk_fma(vf2 a, vf2 b, vf2 c) {
    vf2 d;
    asm("v_pk_fma_f32 %0, %1, %2, %3" : "=v"(d) : "v"(a), "v"(b), "v"(c));
    return d;
}
__device__ __forceinline__ vf2 pk_mul(vf2 a, vf2 b) {
    vf2 d;
    asm("v_pk_mul_f32 %0, %1, %2" : "=v"(d) : "v"(a), "v"(b));
    return d;
}
// weight-broadcast pk_fma: use LO (resp. HI) word of w for BOTH lanes.
__device__ __forceinline__ vf2 pk_fma_blo(vf2 w, vf2 b, vf2 c) {
    vf2 d;
    asm("v_pk_fma_f32 %0, %1, %2, %3 op_sel_hi:[0,1,1]"
        : "=v"(d) : "v"(w), "v"(b), "v"(c));
    return d;
}
__device__ __forceinline__ vf2 pk_fma_bhi(vf2 w, vf2 b, vf2 c) {
    vf2 d;
    asm("v_pk_fma_f32 %0, %1, %2, %3 op_sel:[1,0,0] op_sel_hi:[1,1,1]"
        : "=v"(d) : "v"(w), "v"(b), "v"(c));
    return d;
}

// ================= streaming level-0 kernel (r16 verbatim) =================
#define L0_H 512
#define L0_HOUT 502
#define L0_HP 256
#define L0_SEG 64
#define L0_NCHUNK 7                 // ceil((SEG+10)/11)
#define ROWW 536                    // 268 staged cols x (P,Q) words
#define NQ 134                      // quads per row
#define BUF_WORDS (11 * ROWW)       // 5896 per buffer
#define CARRY0 (2 * BUF_WORDS)      // 11792
#define STREAM_WORDS (CARRY0 + 2 * ROWW)   // 12864 words = 51456 B -> 3 blocks/CU

__global__ __launch_bounds__(256)
void msssim_stream_l0(const float* __restrict__ img1,
                      const float* __restrict__ img2,
                      double* __restrict__ sums,
                      float* __restrict__ poolP, float* __restrict__ poolQ)
{
    __shared__ __align__(16) float buf[STREAM_WORDS];
    __shared__ float wred[4][2];

    const float gs[11] = {0.00102838f, 0.00759875f, 0.03600077f, 0.10936070f,
                          0.21300554f, 0.26601173f, 0.21300554f, 0.10936070f,
                          0.03600077f, 0.00759875f, 0.00102838f};

    const int tid = threadIdx.x;
    const int c0 = blockIdx.x * 256;          // strip base col
    const int oy0 = blockIdx.y * L0_SEG;      // seg base output row
    const long long plane = (long long)blockIdx.z * L0_H * L0_H;
    const long long pplane = (long long)blockIdx.z * L0_HP * L0_HP;
    const bool colok = (c0 + tid) < L0_HOUT;

    const int par = tid & 1;
    vf2 wp[6];
    #pragma unroll
    for (int jq = 0; jq < 6; ++jq) {
        const int i0 = 2 * jq, i1 = 2 * jq + 1;
        const float we0 = (i0 < 11) ? gs[i0] : 0.f;
        const float wo0 = (i0 >= 1) ? gs[i0 - 1] : 0.f;
        const float we1 = (i1 < 11) ? gs[i1] : 0.f;
        const float wo1 = (i1 >= 1) ? gs[i1 - 1] : 0.f;
        wp[jq].x = par ? wo0 : we0;
        wp[jq].y = par ? wo1 : we1;
    }
    vf2 wgv[6];
    #pragma unroll
    for (int k = 0; k < 6; ++k) { wgv[k].x = gs[k]; wgv[k].y = gs[k]; }

    int rowS[6], colS[6], ldsoff[6], rHS[6];
    #pragma unroll
    for (int t = 0; t < 6; ++t) {
        const int s = tid + 256 * t;
        if (s < 11 * NQ) {
            const int r = s / NQ, q = s - NQ * r;
            rowS[t] = r;
            colS[t] = c0 + 2 * q;
            ldsoff[t] = r * ROWW + q * 4;
            rHS[t] = r * L0_H;
        } else { rowS[t] = -1; colS[t] = 0; ldsoff[t] = 0; rHS[t] = 0; }
    }

    float4 pf[6];
    auto prefetch = [&](int ybase) {
        const int yH = ybase * L0_H;
        #pragma unroll
        for (int t = 0; t < 6; ++t) {
            float2 a = make_float2(0.f, 0.f), b = make_float2(0.f, 0.f);
            if (rowS[t] >= 0) {
                const int y = ybase + rowS[t];
                if (y < L0_H && colS[t] < L0_H) {
                    const long long idx = plane + yH + rHS[t] + colS[t];
                    a = *(const float2*)(img1 + idx);
                    b = *(const float2*)(img2 + idx);
                }
            }
            pf[t] = make_float4(a.x + b.x, a.x - b.x, a.y + b.y, a.y - b.y);
        }
    };
    auto stage_write = [&](int base) {
        #pragma unroll
        for (int t = 0; t < 6; ++t)
            if (rowS[t] >= 0) *(float4*)&buf[base + ldsoff[t]] = pf[t];
    };

    prefetch(oy0);
    stage_write(0);
    __syncthreads();

    vf2 pd_pq[11], pd_sq[11];
    #pragma unroll
    for (int s = 0; s < 11; ++s) { pd_pq[s] = (vf2){0.f, 0.f}; pd_sq[s] = (vf2){0.f, 0.f}; }

    const int qb4 = (tid >> 1) * 4;
    const float C1 = 4.0e-4f, C2 = 3.6e-3f;
    float ssim_acc = 0.f, cs_acc = 0.f;

    for (int c = 0; c < L0_NCHUNK; ++c) {
        const int cs = oy0 + 11 * c;
        const bool more = (c + 1 < L0_NCHUNK);
        const int cb = (c & 1) * BUF_WORDS;
        const int nb = ((c + 1) & 1) * BUF_WORDS;

        if (more) prefetch(cs + 11);

        if (tid < 128) {
            const int px = (c0 >> 1) + tid;
            const int t4 = tid * 4;
            for (int jp = (cs & 1); jp + 1 <= 10; jp += 2) {
                const int py = (cs + jp) >> 1;
                if (py < L0_HP) {
                    const float4 v0 = *(const float4*)&buf[cb + jp * ROWW + t4];
                    const float4 v1 = *(const float4*)&buf[cb + (jp + 1) * ROWW + t4];
                    poolP[pplane + py * L0_HP + px] = 0.25f * (v0.x + v0.z + v1.x + v1.z);
                    poolQ[pplane + py * L0_HP + px] = 0.25f * (v0.y + v0.w + v1.y + v1.w);
                }
            }
            if (c > 0 && (cs & 1)) {
                const int py = (cs - 1) >> 1;
                if (py < L0_HP) {
                    const float4 v0 = *(const float4*)&buf[CARRY0 + ((c - 1) & 1) * ROWW + t4];
                    const float4 v1 = *(const float4*)&buf[cb + t4];
                    poolP[pplane + py * L0_HP + px] = 0.25f * (v0.x + v0.z + v1.x + v1.z);
                    poolQ[pplane + py * L0_HP + px] = 0.25f * (v0.y + v0.w + v1.y + v1.w);
                }
            }
        }
        if (((cs & 1) == 0) && more && tid < NQ) {
            *(float4*)&buf[CARRY0 + (c & 1) * ROWW + tid * 4] =
                *(const float4*)&buf[cb + 10 * ROWW + tid * 4];
        }

        #pragma unroll
        for (int j = 0; j < 11; ++j) {
            pd_pq[j] = (vf2){0.f, 0.f};
            pd_sq[j] = (vf2){0.f, 0.f};

            float4 q[6];
            const int rw = cb + j * ROWW + qb4;
            #pragma unroll
            for (int u = 0; u < 6; ++u) q[u] = *(const float4*)&buf[rw + 4 * u];

            vf2 hpq = {0.f, 0.f}, hsq = {0.f, 0.f};
            #pragma unroll
            for (int u = 0; u < 6; ++u) {
                const vf2 elo = {q[u].x, q[u].y};
                const vf2 ehi = {q[u].z, q[u].w};
                const vf2 slo = pk_mul(elo, elo);
                const vf2 shi = pk_mul(ehi, ehi);
                hpq = pk_fma_blo(wp[u], elo, hpq);
                hpq = pk_fma_bhi(wp[u], ehi, hpq);
                hsq = pk_fma_blo(wp[u], slo, hsq);
                hsq = pk_fma_bhi(wp[u], shi, hsq);
            }
            #pragma unroll
            for (int k = 0; k < 11; ++k) {
                const int s = (j - k + 11) % 11;       // static
                const int m = (k <= 5) ? k : 10 - k;   // static
                pd_pq[s] = pk_fma(wgv[m], hpq, pd_pq[s]);
                pd_sq[s] = pk_fma(wgv[m], hsq, pd_sq[s]);
            }
            const int yrel = 11 * c + j;
            if (yrel >= 10) {
                const int s = (j + 1) % 11;            // static
                const int orow = yrel - 10;
                if (orow < L0_SEG && (oy0 + orow) < L0_HOUT && colok) {
                    const vf2 musq = pk_mul(pd_pq[s], pd_pq[s]);
                    const float sP = pd_sq[s].x - musq.x;
                    const float sQ = pd_sq[s].y - musq.y;
                    const float v1 = 0.5f * (sP - sQ) + C2;
                    const float v2 = 0.5f * (sP + sQ) + C2;
                    const float num1 = 0.5f * (musq.x - musq.y) + C1;
                    const float den1 = 0.5f * (musq.x + musq.y) + C1;
                    cs_acc += v1 * __builtin_amdgcn_rcpf(v2);
                    ssim_acc += num1 * v1 * __builtin_amdgcn_rcpf(den1 * v2);
                }
            }
        }

        if (more) stage_write(nb);
        __syncthreads();
    }

    #pragma unroll
    for (int off = 32; off > 0; off >>= 1) {
        ssim_acc += __shfl_down(ssim_acc, off);
        cs_acc   += __shfl_down(cs_acc, off);
    }
    const int wave = tid >> 6;
    if ((tid & 63) == 0) { wred[wave][0] = ssim_acc; wred[wave][1] = cs_acc; }
    __syncthreads();
    if (tid == 0) {
        atomicAdd(&sums[0], (double)(wred[0][0] + wred[1][0] + wred[2][0] + wred[3][0]));
        atomicAdd(&sums[5], (double)(wred[0][1] + wred[1][1] + wred[2][1] + wred[3][1]));
    }
}

// ================= pool cascade: L1 input -> L2,L3,L4 inputs =================
// One block per (plane, image): 2x2 pool X(256^2)->Y(128^2) (LDS+global),
// then Y->Z(64^2), then Z->W(32^2). Same left-assoc 2x2 sum order as the
// fused pools it replaces. 96 blocks, LDS 80KB -> 2 blocks/CU.
__global__ __launch_bounds__(256)
void msssim_pool_cascade(const float* __restrict__ X1, const float* __restrict__ X2,
                         float* __restrict__ Y1, float* __restrict__ Y2,
                         float* __restrict__ Z1, float* __restrict__ Z2,
                         float* __restrict__ W1, float* __restrict__ W2)
{
    __shared__ float ys[16384];
    __shared__ float zs[4096];
    const int tid = threadIdx.x;
    const int plane = blockIdx.x >> 1;
    const int img = blockIdx.x & 1;
    const float* src = (img ? X2 : X1) + (long long)plane * 65536;
    float* yg = (img ? Y2 : Y1) + (long long)plane * 16384;
    float* zg = (img ? Z2 : Z1) + (long long)plane * 4096;
    float* wg = (img ? W2 : W1) + (long long)plane * 1024;

    for (int i = tid; i < 16384; i += 256) {
        const int y = i >> 7, x = i & 127;
        const float2 t0 = *(const float2*)&src[(2 * y) * 256 + 2 * x];
        const float2 t1 = *(const float2*)&src[(2 * y + 1) * 256 + 2 * x];
        const float v = 0.25f * (t0.x + t0.y + t1.x + t1.y);
        ys[i] = v; yg[i] = v;
    }
    __syncthreads();
    for (int i = tid; i < 4096; i += 256) {
        const int y = i >> 6, x = i & 63;
        const float v = 0.25f * (ys[(2 * y) * 128 + 2 * x] + ys[(2 * y) * 128 + 2 * x + 1]
                               + ys[(2 * y + 1) * 128 + 2 * x] + ys[(2 * y + 1) * 128 + 2 * x + 1]);
        zs[i] = v; zg[i] = v;
    }
    __syncthreads();
    for (int i = tid; i < 1024; i += 256) {
        const int y = i >> 5, x = i & 31;
        wg[i] = 0.25f * (zs[(2 * y) * 64 + 2 * x] + zs[(2 * y) * 64 + 2 * x + 1]
                       + zs[(2 * y + 1) * 64 + 2 * x] + zs[(2 * y + 1) * 64 + 2 * x + 1]);
    }
}

// ================= fused SSIM for levels 1-4 (one launch) =================
// Flat grid 1776 blocks: [0,768) L1 (8 strips x 2 segs x 48, tps=4);
// [768,1536) L2 (4x4x48, tps=1); [1536,1728) L3 (2x2x48); [1728,1776) L4.
// Body = proven phase kernel, pq inputs, NO pool (cascade owns pooling).
#define TILE 32
#define IN_DIM 42
#define SCP 21
#define HALO 10
#define STAGE_WORDS (IN_DIM * SCP * 4)
#define SH 340
#define HB STAGE_WORDS
#define SMEM_WORDS (HB + 16 * SH)

__global__ __launch_bounds__(256)
void msssim_fused_levels(const float* __restrict__ X1, const float* __restrict__ X2,
                         const float* __restrict__ Y1, const float* __restrict__ Y2,
                         const float* __restrict__ Z1, const float* __restrict__ Z2,
                         const float* __restrict__ W1, const float* __restrict__ W2,
                         double* __restrict__ sums)
{
    __shared__ __align__(16) float smem[SMEM_WORDS];
    __shared__ float wred[4][2];

    // ---- decode (level, plane, strip, seg) from flat block id
    const int bid = blockIdx.x;
    const float *src1, *src2;
    int H, level, strip, seg, plane, tps;
    if (bid < 768) {
        level = 1; H = 256; src1 = X1; src2 = X2; tps = 4;
        const int r = bid;        plane = r >> 4; const int t = r & 15; strip = t & 7; seg = t >> 3;
    } else if (bid < 1536) {
        level = 2; H = 128; src1 = Y1; src2 = Y2; tps = 1;
        const int r = bid - 768;  plane = r >> 4; const int t = r & 15; strip = t & 3; seg = t >> 2;
    } else if (bid < 1728) {
        level = 3; H = 64;  src1 = Z1; src2 = Z2; tps = 1;
        const int r = bid - 1536; plane = r >> 2; const int t = r & 3;  strip = t & 1; seg = t >> 1;
    } else {
        level = 4; H = 32;  src1 = W1; src2 = W2; tps = 1;
        plane = bid - 1728; strip = 0; seg = 0;
    }

    const float g[11] = {0.00102838f, 0.00759875f, 0.03600077f, 0.10936070f,
                         0.21300554f, 0.26601173f, 0.21300554f, 0.10936070f,
                         0.03600077f, 0.00759875f, 0.00102838f};
    vf2 wg[11];
    #pragma unroll
    for (int k = 0; k < 11; ++k) { wg[k].x = g[k]; wg[k].y = g[k]; }

    const int tid = threadIdx.x;
    const int Hout = H - HALO;
    const int ntiles = (Hout + TILE - 1) / TILE;
    const int tstart = seg * tps;
    const int tend = min(ntiles, tstart + tps);
    const int ox0 = strip * TILE;
    const long long base = (long long)plane * H * H;

    int rHS[4], rS[4], xS[4];
    #pragma unroll
    for (int t4 = 0; t4 < 4; ++t4) {
        const int s = tid + 256 * t4;
        if (s < IN_DIM * SCP) {
            const int r = s / SCP, cp = s - r * SCP;
            rS[t4] = r; rHS[t4] = r * H; xS[t4] = ox0 + 2 * cp;
        } else { rS[t4] = -1; rHS[t4] = 0; xS[t4] = 0; }
    }

    auto load_slot = [&](int t4, int ybase) -> float4 {
        float2 a = make_float2(0.f, 0.f), b = make_float2(0.f, 0.f);
        if (rS[t4] >= 0) {
            const int y = ybase + rS[t4], x = xS[t4];
            if (y < H && x < H) {
                const long long idx = base + (long long)ybase * H + rHS[t4] + x;
                a = *(const float2*)(src1 + idx);
                b = *(const float2*)(src2 + idx);
            }
        }
        return make_float4(a.x, b.x, a.y, b.y);   // (P0,Q0,P1,Q1)
    };

    float4 pref[4];
    {
        #pragma unroll
        for (int t4 = 0; t4 < 4; ++t4) pref[t4] = load_slot(t4, tstart * TILE);
        #pragma unroll
        for (int t4 = 0; t4 < 4; ++t4)
            if (rS[t4] >= 0) *(float4*)&smem[(tid + 256 * t4) * 4] = pref[t4];
    }
    __syncthreads();

    float ssim_acc = 0.f, cs_acc = 0.f;

    for (int tt = tstart; tt < tend; ++tt) {
        const int ty0 = tt * TILE;
        const bool more = (tt + 1 < tend);

        if (more) {
            #pragma unroll
            for (int t4 = 0; t4 < 4; ++t4) pref[t4] = load_slot(t4, ty0 + TILE);
        }

        float4 hA[3], hBv[3];
        #pragma unroll
        for (int t = 0; t < 3; ++t) {
            const int p = tid + 256 * t;
            if (p < IN_DIM * 16) {
                const int r = p >> 4, m = p & 15;
                vf2 Apq = {0.f, 0.f}, Asq = {0.f, 0.f};
                vf2 Bpq = {0.f, 0.f}, Bsq = {0.f, 0.f};
                #pragma unroll
                for (int jj = 0; jj < 6; ++jj) {
                    const float4 v = *(const float4*)&smem[(r * SCP + m + jj) * 4];
                    const vf2 lo = {v.x, v.y};
                    const vf2 hi = {v.z, v.w};
                    const vf2 losq = pk_mul(lo, lo);
                    const vf2 hisq = pk_mul(hi, hi);
                    Apq = pk_fma(wg[2 * jj], lo, Apq);
                    Asq = pk_fma(wg[2 * jj], losq, Asq);
                    if (jj >= 1) {
                        Bpq = pk_fma(wg[2 * jj - 1], lo, Bpq);
                        Bsq = pk_fma(wg[2 * jj - 1], losq, Bsq);
                    }
                    if (jj <= 4) {
                        Apq = pk_fma(wg[2 * jj + 1], hi, Apq);
                        Asq = pk_fma(wg[2 * jj + 1], hisq, Asq);
                    }
                    Bpq = pk_fma(wg[2 * jj], hi, Bpq);
                    Bsq = pk_fma(wg[2 * jj], hisq, Bsq);
                }
                hA[t]  = make_float4(Apq.x, Apq.y, Asq.x, Asq.y);
                hBv[t] = make_float4(Bpq.x, Bpq.y, Bsq.x, Bsq.y);
            }
        }
        __syncthreads();

        #pragma unroll
        for (int t = 0; t < 3; ++t) {
            const int p = tid + 256 * t;
            if (p < IN_DIM * 16) {
                const int r = p >> 4, m = p & 15;
                const int hb = HB + m * SH + r * 8;
                *(float4*)&smem[hb]     = hA[t];
                *(float4*)&smem[hb + 4] = hBv[t];
            }
        }
        if (more) {
            #pragma unroll
            for (int t4 = 0; t4 < 4; ++t4)
                if (rS[t4] >= 0) *(float4*)&smem[(tid + 256 * t4) * 4] = pref[t4];
        }
        __syncthreads();

        const int tx = tid & 31, rg = tid >> 5;
        const int r0 = rg * 4;
        const int m = tx >> 1, par = tx & 1;
        const int hb = HB + m * SH + par * 4;

        vf2 accPQ[4], accSQ[4];
        #pragma unroll
        for (int o = 0; o < 4; ++o) {
            accPQ[o] = (vf2){0.f, 0.f};
            accSQ[o] = (vf2){0.f, 0.f};
        }
        #pragma unroll
        for (int i = 0; i < 14; ++i) {
            const float4 h4 = *(const float4*)&smem[hb + (r0 + i) * 8];
            const vf2 ppq = {h4.x, h4.y};
            const vf2 psq = {h4.z, h4.w};
            #pragma unroll
            for (int o = 0; o < 4; ++o) {
                const int k = i - o;
                if (k >= 0 && k <= 10) {
                    accPQ[o] = pk_fma(wg[k], ppq, accPQ[o]);
                    accSQ[o] = pk_fma(wg[k], psq, accSQ[o]);
                }
            }
        }

        const float C1 = 4.0e-4f;
        const float C2 = 3.6e-3f;
        const int ox = ox0 + tx;
        #pragma unroll
        for (int o = 0; o < 4; ++o) {
            const int oy = ty0 + r0 + o;
            if (oy < Hout && ox < Hout) {
                const vf2 musq = pk_mul(accPQ[o], accPQ[o]);
                const float sP = accSQ[o].x - musq.x;
                const float sQ = accSQ[o].y - musq.y;
                const float v1 = 0.5f * (sP - sQ) + C2;
                const float v2 = 0.5f * (sP + sQ) + C2;
                const float num1 = 0.5f * (musq.x - musq.y) + C1;
                const float den1 = 0.5f * (musq.x + musq.y) + C1;
                cs_acc += v1 * __builtin_amdgcn_rcpf(v2);
                ssim_acc += num1 * v1 * __builtin_amdgcn_rcpf(den1 * v2);
            }
        }
    }

    #pragma unroll
    for (int off = 32; off > 0; off >>= 1) {
        ssim_acc += __shfl_down(ssim_acc, off);
        cs_acc   += __shfl_down(cs_acc, off);
    }
    const int wave = tid >> 6;
    if ((tid & 63) == 0) { wred[wave][0] = ssim_acc; wred[wave][1] = cs_acc; }
    __syncthreads();
    if (tid == 0) {
        const float s = wred[0][0] + wred[1][0] + wred[2][0] + wred[3][0];
        const float c = wred[0][1] + wred[1][1] + wred[2][1] + wred[3][1];
        atomicAdd(&sums[level],     (double)s);
        atomicAdd(&sums[5 + level], (double)c);
    }
}

// -------------------- final combine --------------------
__global__ void msssim_final_kernel(const double* __restrict__ sums,
                                    float* __restrict__ out)
{
    if (threadIdx.x == 0 && blockIdx.x == 0) {
        const double W[5] = {0.0448, 0.2856, 0.3001, 0.2363, 0.1333};
        const int Houts[5] = {502, 246, 118, 54, 22};
        double mssim[5], mcs[5];
        for (int l = 0; l < 5; ++l) {
            const double cnt = 48.0 * (double)Houts[l] * (double)Houts[l];
            mssim[l] = (sums[l]     / cnt + 1.0) * 0.5;
            mcs[l]   = (sums[5 + l] / cnt + 1.0) * 0.5;
        }
        const double p2 = pow(mssim[4], W[4]);
        double prod = 1.0;
        for (int l = 0; l < 4; ++l) prod *= pow(mcs[l], W[l]) * p2;
        out[0] = (float)(1.0 - prod);
    }
}

// -------------------- launch --------------------
extern "C" void kernel_launch(void* const* d_in, const int* in_sizes, int n_in,
                              void* d_out, int out_size, void* d_ws, size_t ws_size,
                              hipStream_t stream)
{
    const float* img1 = (const float*)d_in[0];
    const float* img2 = (const float*)d_in[1];
    float* out = (float*)d_out;
    (void)in_sizes; (void)n_in; (void)out_size; (void)ws_size;

    char* ws = (char*)d_ws;
    double* sums = (double*)ws;                      // 10 doubles
    float* X1 = (float*)(ws + 256);                  // 48 x 256^2 (L1 P)
    float* X2 = X1 + 3145728;                        // L1 Q
    float* Y1 = X2 + 3145728;                        // 48 x 128^2 (L2 P)
    float* Y2 = Y1 + 786432;
    float* Z1 = Y2 + 786432;                         // 48 x 64^2 (L3 P)
    float* Z2 = Z1 + 196608;
    float* W1 = Z2 + 196608;                         // 48 x 32^2 (L4 P)
    float* W2 = W1 + 49152;                          // total ~33.4 MB

    hipMemsetAsync(sums, 0, 10 * sizeof(double), stream);

    // level 0: streaming kernel (produces sums[0], sums[5] and X = L1 input)
    hipLaunchKernelGGL(msssim_stream_l0, dim3(2, 8, 48), dim3(256), 0, stream,
                       img1, img2, sums, X1, X2);

    // pool cascade: X -> Y, Z, W (breaks the L1->L2->L3->L4 dependency chain)
    hipLaunchKernelGGL(msssim_pool_cascade, dim3(96), dim3(256), 0, stream,
                       X1, X2, Y1, Y2, Z1, Z2, W1, W2);

    // levels 1-4 fused in ONE launch (1776 blocks, no inter-level deps)
    hipLaunchKernelGGL(msssim_fused_levels, dim3(1776), dim3(256), 0, stream,
                       X1, X2, Y1, Y2, Z1, Z2, W1, W2, sums);

    hipLaunchKernelGGL(msssim_final_kernel, dim3(1), dim3(64), 0, stream, sums, out);
}

// Round 18
// 129.780 us; speedup vs baseline: 1.1701x; 1.0157x over previous
//
#include <hip/hip_runtime.h>
#include <math.h>

typedef float vf2 __attribute__((ext_vector_type(2)));

// ---------------- packed dual-fp32 helpers (VOP3P) ----------------
__device__ __forceinline__ vf2 pk_fma(vf2 a, vf2 b, vf2 c) {
    vf2 d;
    asm("v_pk_fma_f32 %0, %1, %2, %3" : "=v"(d) : "v"(a), "v"(b), "v"(c));
    return d;
}
__device__ __forceinline__ vf2 pk_mul(vf2 a, vf2 b) {
    vf2 d;
    asm("v_pk_mul_f32 %0, %1, %2" : "=v"(d) : "v"(a), "v"(b));
    return d;
}
__device__ __forceinline__ vf2 pk_fma_blo(vf2 w, vf2 b, vf2 c) {
    vf2 d;
    asm("v_pk_fma_f32 %0, %1, %2, %3 op_sel_hi:[0,1,1]"
        : "=v"(d) : "v"(w), "v"(b), "v"(c));
    return d;
}
__device__ __forceinline__ vf2 pk_fma_bhi(vf2 w, vf2 b, vf2 c) {
    vf2 d;
    asm("v_pk_fma_f32 %0, %1, %2, %3 op_sel:[1,0,0] op_sel_hi:[1,1,1]"
        : "=v"(d) : "v"(w), "v"(b), "v"(c));
    return d;
}

#define L0_H 512
#define L0_HOUT 502
#define L0_SEG 64
#define L0_NCHUNK 7
#define ROWW 536                    // 268 staged cols x (P,Q) words
#define NQ 134                      // quads per row
#define L0_BUF (11 * ROWW)          // 5896 words

#define TILE 32
#define IN_DIM 42
#define SCP 21
#define HALO 10
#define LV_STAGE (IN_DIM * SCP * 4) // 3528
#define SH 340
#define HB LV_STAGE
#define MEGA_WORDS (HB + 16 * SH)   // 8968 words = 35872 B -> 4 blocks/CU

// ================= cascade: originals -> Y,Z,W (bit-identical pool chain) ====
// Block = (plane, region): region r owns pool1 rows [16r,16r+16) x 256 cols.
// pool1 value == old X == L0's fused pool (P per pixel, then 2x2 sum, x0.25).
// Then Y rows [8r,+8), Z rows [4r,+4), W rows [2r,+2) — same op order as the
// r17 cascade. 768 blocks.
__global__ __launch_bounds__(256)
void msssim_cascade(const float* __restrict__ img1, const float* __restrict__ img2,
                    float* __restrict__ Y1, float* __restrict__ Y2,
                    float* __restrict__ Z1, float* __restrict__ Z2,
                    float* __restrict__ W1, float* __restrict__ W2)
{
    __shared__ float xs[16 * 256 * 2];   // pool1 band (P,Q interleaved)
    __shared__ float ysh[8 * 128 * 2];
    __shared__ float zsh[4 * 64 * 2];
    const int tid = threadIdx.x;
    const int reg = blockIdx.x & 15, plane = blockIdx.x >> 4;
    const long long obase = (long long)plane * 262144;

    for (int i = tid; i < 16 * 256; i += 256) {
        const int r = i >> 8, c = i & 255;
        const long long o = obase + (long long)(2 * (16 * reg + r)) * 512 + 2 * c;
        const float2 a0 = *(const float2*)&img1[o];
        const float2 a1 = *(const float2*)&img1[o + 512];
        const float2 b0 = *(const float2*)&img2[o];
        const float2 b1 = *(const float2*)&img2[o + 512];
        xs[2 * i]     = 0.25f * ((a0.x + b0.x) + (a0.y + b0.y) + (a1.x + b1.x) + (a1.y + b1.y));
        xs[2 * i + 1] = 0.25f * ((a0.x - b0.x) + (a0.y - b0.y) + (a1.x - b1.x) + (a1.y - b1.y));
    }
    __syncthreads();
    for (int i = tid; i < 8 * 128; i += 256) {
        const int r = i >> 7, c = i & 127;
        const int i00 = ((2 * r) * 256 + 2 * c) * 2;
        const float yP = 0.25f * (xs[i00] + xs[i00 + 2] + xs[i00 + 512] + xs[i00 + 514]);
        const float yQ = 0.25f * (xs[i00 + 1] + xs[i00 + 3] + xs[i00 + 513] + xs[i00 + 515]);
        ysh[2 * i] = yP; ysh[2 * i + 1] = yQ;
        const long long yo = (long long)plane * 16384 + (long long)(8 * reg + r) * 128 + c;
        Y1[yo] = yP; Y2[yo] = yQ;
    }
    __syncthreads();
    for (int i = tid; i < 4 * 64; i += 256) {
        const int r = i >> 6, c = i & 63;
        const int i00 = ((2 * r) * 128 + 2 * c) * 2;
        const float zP = 0.25f * (ysh[i00] + ysh[i00 + 2] + ysh[i00 + 256] + ysh[i00 + 258]);
        const float zQ = 0.25f * (ysh[i00 + 1] + ysh[i00 + 3] + ysh[i00 + 257] + ysh[i00 + 259]);
        zsh[2 * i] = zP; zsh[2 * i + 1] = zQ;
        const long long zo = (long long)plane * 4096 + (long long)(4 * reg + r) * 64 + c;
        Z1[zo] = zP; Z2[zo] = zQ;
    }
    __syncthreads();
    for (int i = tid; i < 2 * 32; i += 256) {
        const int r = i >> 5, c = i & 31;
        const int i00 = ((2 * r) * 64 + 2 * c) * 2;
        const long long wo = (long long)plane * 1024 + (long long)(2 * reg + r) * 32 + c;
        W1[wo] = 0.25f * (zsh[i00] + zsh[i00 + 2] + zsh[i00 + 128] + zsh[i00 + 130]);
        W2[wo] = 0.25f * (zsh[i00 + 1] + zsh[i00 + 3] + zsh[i00 + 129] + zsh[i00 + 131]);
    }
}

// ================= MEGA: L0 (768) + L1-inline (768) + L2/L3/L4 (1008) =======
// No cross-block dependencies: L0 no longer pools (X eliminated); L1 pools
// its input from the ORIGINALS inline in load_slot (bit-identical X values);
// L2/3/4 read Y/Z/W from the cascade kernel. LDS 35,872B -> 4 blocks/CU, so
// level blocks co-reside with L0 blocks and fill idle issue slots.
__global__ __launch_bounds__(256)
void msssim_mega(const float* __restrict__ img1, const float* __restrict__ img2,
                 const float* __restrict__ Y1, const float* __restrict__ Y2,
                 const float* __restrict__ Z1, const float* __restrict__ Z2,
                 const float* __restrict__ W1, const float* __restrict__ W2,
                 double* __restrict__ sums)
{
    __shared__ __align__(16) float smem[MEGA_WORDS];
    __shared__ float wred[4][2];

    const float gs[11] = {0.00102838f, 0.00759875f, 0.03600077f, 0.10936070f,
                          0.21300554f, 0.26601173f, 0.21300554f, 0.10936070f,
                          0.03600077f, 0.00759875f, 0.00102838f};
    const int tid = threadIdx.x;
    const int bid = blockIdx.x;
    const float C1 = 4.0e-4f, C2 = 3.6e-3f;
    float ssim_acc = 0.f, cs_acc = 0.f;
    int level;

    if (bid < 768) {
        // ======================= L0 streaming role =======================
        level = 0;
        const int c0 = (bid & 1) * 256;
        const int oy0 = ((bid >> 1) & 7) * L0_SEG;
        const long long plane = (long long)(bid >> 4) * 262144;
        const bool colok = (c0 + tid) < L0_HOUT;

        const int par = tid & 1;
        vf2 wp[6];
        #pragma unroll
        for (int jq = 0; jq < 6; ++jq) {
            const int i0 = 2 * jq, i1 = 2 * jq + 1;
            const float we0 = (i0 < 11) ? gs[i0] : 0.f;
            const float wo0 = (i0 >= 1) ? gs[i0 - 1] : 0.f;
            const float we1 = (i1 < 11) ? gs[i1] : 0.f;
            const float wo1 = (i1 >= 1) ? gs[i1 - 1] : 0.f;
            wp[jq].x = par ? wo0 : we0;
            wp[jq].y = par ? wo1 : we1;
        }
        vf2 wgv[6];
        #pragma unroll
        for (int k = 0; k < 6; ++k) { wgv[k].x = gs[k]; wgv[k].y = gs[k]; }

        int rowS[6], colS[6], ldsoff[6], rHS[6];
        #pragma unroll
        for (int t = 0; t < 6; ++t) {
            const int s = tid + 256 * t;
            if (s < 11 * NQ) {
                const int r = s / NQ, q = s - NQ * r;
                rowS[t] = r; colS[t] = c0 + 2 * q;
                ldsoff[t] = r * ROWW + q * 4; rHS[t] = r * L0_H;
            } else { rowS[t] = -1; colS[t] = 0; ldsoff[t] = 0; rHS[t] = 0; }
        }

        float4 pf[6];
        auto prefetch = [&](int ybase) {
            const int yH = ybase * L0_H;
            #pragma unroll
            for (int t = 0; t < 6; ++t) {
                float2 a = make_float2(0.f, 0.f), b = make_float2(0.f, 0.f);
                if (rowS[t] >= 0) {
                    const int y = ybase + rowS[t];
                    if (y < L0_H && colS[t] < L0_H) {
                        const long long idx = plane + yH + rHS[t] + colS[t];
                        a = *(const float2*)(img1 + idx);
                        b = *(const float2*)(img2 + idx);
                    }
                }
                pf[t] = make_float4(a.x + b.x, a.x - b.x, a.y + b.y, a.y - b.y);
            }
        };
        auto stage_write = [&]() {
            #pragma unroll
            for (int t = 0; t < 6; ++t)
                if (rowS[t] >= 0) *(float4*)&smem[ldsoff[t]] = pf[t];
        };

        prefetch(oy0);
        stage_write();
        __syncthreads();

        vf2 pd_pq[11], pd_sq[11];
        #pragma unroll
        for (int s = 0; s < 11; ++s) { pd_pq[s] = (vf2){0.f, 0.f}; pd_sq[s] = (vf2){0.f, 0.f}; }

        const int qb4 = (tid >> 1) * 4;

        for (int c = 0; c < L0_NCHUNK; ++c) {
            const bool more = (c + 1 < L0_NCHUNK);
            if (more) prefetch(oy0 + 11 * (c + 1));

            #pragma unroll
            for (int j = 0; j < 11; ++j) {
                pd_pq[j] = (vf2){0.f, 0.f};
                pd_sq[j] = (vf2){0.f, 0.f};

                float4 q[6];
                const int rw = j * ROWW + qb4;
                #pragma unroll
                for (int u = 0; u < 6; ++u) q[u] = *(const float4*)&smem[rw + 4 * u];

                vf2 hpq = {0.f, 0.f}, hsq = {0.f, 0.f};
                #pragma unroll
                for (int u = 0; u < 6; ++u) {
                    const vf2 elo = {q[u].x, q[u].y};
                    const vf2 ehi = {q[u].z, q[u].w};
                    const vf2 slo = pk_mul(elo, elo);
                    const vf2 shi = pk_mul(ehi, ehi);
                    hpq = pk_fma_blo(wp[u], elo, hpq);
                    hpq = pk_fma_bhi(wp[u], ehi, hpq);
                    hsq = pk_fma_blo(wp[u], slo, hsq);
                    hsq = pk_fma_bhi(wp[u], shi, hsq);
                }
                #pragma unroll
                for (int k = 0; k < 11; ++k) {
                    const int s = (j - k + 11) % 11;
                    const int m = (k <= 5) ? k : 10 - k;
                    pd_pq[s] = pk_fma(wgv[m], hpq, pd_pq[s]);
                    pd_sq[s] = pk_fma(wgv[m], hsq, pd_sq[s]);
                }
                const int yrel = 11 * c + j;
                if (yrel >= 10) {
                    const int s = (j + 1) % 11;
                    const int orow = yrel - 10;
                    if (orow < L0_SEG && (oy0 + orow) < L0_HOUT && colok) {
                        const vf2 musq = pk_mul(pd_pq[s], pd_pq[s]);
                        const float sP = pd_sq[s].x - musq.x;
                        const float sQ = pd_sq[s].y - musq.y;
                        const float v1 = 0.5f * (sP - sQ) + C2;
                        const float v2 = 0.5f * (sP + sQ) + C2;
                        const float num1 = 0.5f * (musq.x - musq.y) + C1;
                        const float den1 = 0.5f * (musq.x + musq.y) + C1;
                        cs_acc += v1 * __builtin_amdgcn_rcpf(v2);
                        ssim_acc += num1 * v1 * __builtin_amdgcn_rcpf(den1 * v2);
                    }
                }
            }

            __syncthreads();
            if (more) stage_write();
            __syncthreads();
        }
    } else {
        // ======================= levels 1-4 role =======================
        const int id = bid - 768;
        const float *src1 = nullptr, *src2 = nullptr;
        int H, strip, seg, plane, tps;
        if (id < 768) {
            level = 1; H = 256; tps = 4;
            plane = id >> 4; const int t = id & 15; strip = t & 7; seg = t >> 3;
        } else if (id < 1536) {
            level = 2; H = 128; tps = 1; src1 = Y1; src2 = Y2;
            const int r = id - 768; plane = r >> 4; const int t = r & 15; strip = t & 3; seg = t >> 2;
        } else if (id < 1728) {
            level = 3; H = 64; tps = 1; src1 = Z1; src2 = Z2;
            const int r = id - 1536; plane = r >> 2; const int t = r & 3; strip = t & 1; seg = t >> 1;
        } else {
            level = 4; H = 32; tps = 1; src1 = W1; src2 = W2;
            plane = id - 1728; strip = 0; seg = 0;
        }

        vf2 wg[11];
        #pragma unroll
        for (int k = 0; k < 11; ++k) { wg[k].x = gs[k]; wg[k].y = gs[k]; }

        const int Hout = H - HALO;
        const int ntiles = (Hout + TILE - 1) / TILE;
        const int tstart = seg * tps;
        const int tend = min(ntiles, tstart + tps);
        const int ox0 = strip * TILE;
        const long long base = (long long)plane * H * H;
        const long long obase = (long long)plane * 262144;   // originals (L1)

        int rHS[4], rS[4], xS[4];
        #pragma unroll
        for (int t4 = 0; t4 < 4; ++t4) {
            const int s = tid + 256 * t4;
            if (s < IN_DIM * SCP) {
                const int r = s / SCP, cp = s - r * SCP;
                rS[t4] = r; rHS[t4] = r * H; xS[t4] = ox0 + 2 * cp;
            } else { rS[t4] = -1; rHS[t4] = 0; xS[t4] = 0; }
        }

        auto load_slot = [&](int t4, int ybase) -> float4 {
            if (rS[t4] < 0) return make_float4(0.f, 0.f, 0.f, 0.f);
            const int y = ybase + rS[t4], x = xS[t4];
            if (y >= H || x >= H) return make_float4(0.f, 0.f, 0.f, 0.f);
            if (level == 1) {
                // inline 2x2 pool from originals (bit-identical to old X)
                const long long o = obase + (long long)(2 * y) * 512 + 2 * x;
                const float4 A0 = *(const float4*)(img1 + o);
                const float4 A1 = *(const float4*)(img1 + o + 512);
                const float4 B0 = *(const float4*)(img2 + o);
                const float4 B1 = *(const float4*)(img2 + o + 512);
                const float P0 = 0.25f * ((A0.x + B0.x) + (A0.y + B0.y) + (A1.x + B1.x) + (A1.y + B1.y));
                const float Q0 = 0.25f * ((A0.x - B0.x) + (A0.y - B0.y) + (A1.x - B1.x) + (A1.y - B1.y));
                const float P1 = 0.25f * ((A0.z + B0.z) + (A0.w + B0.w) + (A1.z + B1.z) + (A1.w + B1.w));
                const float Q1 = 0.25f * ((A0.z - B0.z) + (A0.w - B0.w) + (A1.z - B1.z) + (A1.w - B1.w));
                return make_float4(P0, Q0, P1, Q1);
            }
            const long long idx = base + (long long)ybase * H + rHS[t4] + x;
            const float2 a = *(const float2*)(src1 + idx);
            const float2 b = *(const float2*)(src2 + idx);
            return make_float4(a.x, b.x, a.y, b.y);   // (P0,Q0,P1,Q1)
        };

        float4 pref[4];
        {
            #pragma unroll
            for (int t4 = 0; t4 < 4; ++t4) pref[t4] = load_slot(t4, tstart * TILE);
            #pragma unroll
            for (int t4 = 0; t4 < 4; ++t4)
                if (rS[t4] >= 0) *(float4*)&smem[(tid + 256 * t4) * 4] = pref[t4];
        }
        __syncthreads();

        for (int tt = tstart; tt < tend; ++tt) {
            const int ty0 = tt * TILE;
            const bool more = (tt + 1 < tend);

            if (more) {
                #pragma unroll
                for (int t4 = 0; t4 < 4; ++t4) pref[t4] = load_slot(t4, ty0 + TILE);
            }

            float4 hA[3], hBv[3];
            #pragma unroll
            for (int t = 0; t < 3; ++t) {
                const int p = tid + 256 * t;
                if (p < IN_DIM * 16) {
                    const int r = p >> 4, m = p & 15;
                    vf2 Apq = {0.f, 0.f}, Asq = {0.f, 0.f};
                    vf2 Bpq = {0.f, 0.f}, Bsq = {0.f, 0.f};
                    #pragma unroll
                    for (int jj = 0; jj < 6; ++jj) {
                        const float4 v = *(const float4*)&smem[(r * SCP + m + jj) * 4];
                        const vf2 lo = {v.x, v.y};
                        const vf2 hi = {v.z, v.w};
                        const vf2 losq = pk_mul(lo, lo);
                        const vf2 hisq = pk_mul(hi, hi);
                        Apq = pk_fma(wg[2 * jj], lo, Apq);
                        Asq = pk_fma(wg[2 * jj], losq, Asq);
                        if (jj >= 1) {
                            Bpq = pk_fma(wg[2 * jj - 1], lo, Bpq);
                            Bsq = pk_fma(wg[2 * jj - 1], losq, Bsq);
                        }
                        if (jj <= 4) {
                            Apq = pk_fma(wg[2 * jj + 1], hi, Apq);
                            Asq = pk_fma(wg[2 * jj + 1], hisq, Asq);
                        }
                        Bpq = pk_fma(wg[2 * jj], hi, Bpq);
                        Bsq = pk_fma(wg[2 * jj], hisq, Bsq);
                    }
                    hA[t]  = make_float4(Apq.x, Apq.y, Asq.x, Asq.y);
                    hBv[t] = make_float4(Bpq.x, Bpq.y, Bsq.x, Bsq.y);
                }
            }
            __syncthreads();

            #pragma unroll
            for (int t = 0; t < 3; ++t) {
                const int p = tid + 256 * t;
                if (p < IN_DIM * 16) {
                    const int r = p >> 4, m = p & 15;
                    const int hb = HB + m * SH + r * 8;
                    *(float4*)&smem[hb]     = hA[t];
                    *(float4*)&smem[hb + 4] = hBv[t];
                }
            }
            if (more) {
                #pragma unroll
                for (int t4 = 0; t4 < 4; ++t4)
                    if (rS[t4] >= 0) *(float4*)&smem[(tid + 256 * t4) * 4] = pref[t4];
            }
            __syncthreads();

            const int tx = tid & 31, rg = tid >> 5;
            const int r0 = rg * 4;
            const int m = tx >> 1, par = tx & 1;
            const int hb = HB + m * SH + par * 4;

            vf2 accPQ[4], accSQ[4];
            #pragma unroll
            for (int o = 0; o < 4; ++o) {
                accPQ[o] = (vf2){0.f, 0.f};
                accSQ[o] = (vf2){0.f, 0.f};
            }
            #pragma unroll
            for (int i = 0; i < 14; ++i) {
                const float4 h4 = *(const float4*)&smem[hb + (r0 + i) * 8];
                const vf2 ppq = {h4.x, h4.y};
                const vf2 psq = {h4.z, h4.w};
                #pragma unroll
                for (int o = 0; o < 4; ++o) {
                    const int k = i - o;
                    if (k >= 0 && k <= 10) {
                        accPQ[o] = pk_fma(wg[k], ppq, accPQ[o]);
                        accSQ[o] = pk_fma(wg[k], psq, accSQ[o]);
                    }
                }
            }

            const int ox = ox0 + tx;
            #pragma unroll
            for (int o = 0; o < 4; ++o) {
                const int oy = ty0 + r0 + o;
                if (oy < Hout && ox < Hout) {
                    const vf2 musq = pk_mul(accPQ[o], accPQ[o]);
                    const float sP = accSQ[o].x - musq.x;
                    const float sQ = accSQ[o].y - musq.y;
                    const float v1 = 0.5f * (sP - sQ) + C2;
                    const float v2 = 0.5f * (sP + sQ) + C2;
                    const float num1 = 0.5f * (musq.x - musq.y) + C1;
                    const float den1 = 0.5f * (musq.x + musq.y) + C1;
                    cs_acc += v1 * __builtin_amdgcn_rcpf(v2);
                    ssim_acc += num1 * v1 * __builtin_amdgcn_rcpf(den1 * v2);
                }
            }
        }
    }

    // ---- block reduction + f64 atomics (both roles)
    #pragma unroll
    for (int off = 32; off > 0; off >>= 1) {
        ssim_acc += __shfl_down(ssim_acc, off);
        cs_acc   += __shfl_down(cs_acc, off);
    }
    const int wave = tid >> 6;
    if ((tid & 63) == 0) { wred[wave][0] = ssim_acc; wred[wave][1] = cs_acc; }
    __syncthreads();
    if (tid == 0) {
        const float s = wred[0][0] + wred[1][0] + wred[2][0] + wred[3][0];
        const float c = wred[0][1] + wred[1][1] + wred[2][1] + wred[3][1];
        atomicAdd(&sums[level],     (double)s);
        atomicAdd(&sums[5 + level], (double)c);
    }
}

// -------------------- final combine --------------------
__global__ void msssim_final_kernel(const double* __restrict__ sums,
                                    float* __restrict__ out)
{
    if (threadIdx.x == 0 && blockIdx.x == 0) {
        const double W[5] = {0.0448, 0.2856, 0.3001, 0.2363, 0.1333};
        const int Houts[5] = {502, 246, 118, 54, 22};
        double mssim[5], mcs[5];
        for (int l = 0; l < 5; ++l) {
            const double cnt = 48.0 * (double)Houts[l] * (double)Houts[l];
            mssim[l] = (sums[l]     / cnt + 1.0) * 0.5;
            mcs[l]   = (sums[5 + l] / cnt + 1.0) * 0.5;
        }
        const double p2 = pow(mssim[4], W[4]);
        double prod = 1.0;
        for (int l = 0; l < 4; ++l) prod *= pow(mcs[l], W[l]) * p2;
        out[0] = (float)(1.0 - prod);
    }
}

// -------------------- launch --------------------
extern "C" void kernel_launch(void* const* d_in, const int* in_sizes, int n_in,
                              void* d_out, int out_size, void* d_ws, size_t ws_size,
                              hipStream_t stream)
{
    const float* img1 = (const float*)d_in[0];
    const float* img2 = (const float*)d_in[1];
    float* out = (float*)d_out;
    (void)in_sizes; (void)n_in; (void)out_size; (void)ws_size;

    char* ws = (char*)d_ws;
    double* sums = (double*)ws;                      // 10 doubles
    float* Y1 = (float*)(ws + 256);                  // 48 x 128^2
    float* Y2 = Y1 + 786432;
    float* Z1 = Y2 + 786432;                         // 48 x 64^2
    float* Z2 = Z1 + 196608;
    float* W1 = Z2 + 196608;                         // 48 x 32^2
    float* W2 = W1 + 49152;

    hipMemsetAsync(sums, 0, 10 * sizeof(double), stream);

    // cascade from ORIGINALS -> Y,Z,W (no dependency on L0)
    hipLaunchKernelGGL(msssim_cascade, dim3(768), dim3(256), 0, stream,
                       img1, img2, Y1, Y2, Z1, Z2, W1, W2);

    // mega: L0 (768) + L1-inline (768) + L2/3/4 (1008) — no cross deps
    hipLaunchKernelGGL(msssim_mega, dim3(2544), dim3(256), 0, stream,
                       img1, img2, Y1, Y2, Z1, Z2, W1, W2, sums);

    hipLaunchKernelGGL(msssim_final_kernel, dim3(1), dim3(64), 0, stream, sums, out);
}